// Round 8
// baseline (121.137 us; speedup 1.0000x reference)
//
#include <hip/hip_runtime.h>
#include <cstdint>
#include <cstddef>

// N=16384, M=64, D=16.  Chunked scan (contractive A => warm-up KK steps).
// Key trick: A is consumed as bf16 by the MFMA, and bf16 == high half of f32,
// so we load ONLY the odd ushorts of A (halves delivered bytes; the delivery
// path, not HBM, is the measured ~6.6 TB/s bottleneck).
#define NN 16384
#define MM 64
#define DD 16
#define CC 64
#define KK 12
#define GG (NN / CC)        // 256 chunks per direction
#define TPB 256             // 4 waves; wave w owns M-tile rows 16w..16w+15
#define ASTR 66             // A LDS row stride (ushorts) -> b32 reads ok
#define FSTR 66             // state row stride (ushorts)

typedef __attribute__((ext_vector_type(8))) __bf16 bf16x8;
typedef __attribute__((ext_vector_type(4))) float f32x4;
typedef unsigned short u16;
typedef unsigned int u32;

typedef const __attribute__((address_space(1))) void* gas_t;
typedef __attribute__((address_space(3))) void* sas_t;

__device__ __forceinline__ void gload_lds16(const void* g, void* l) {
  __builtin_amdgcn_global_load_lds((gas_t)g, (sas_t)l, 16, 0, 0);
}
#define VMWAIT(N) asm volatile("s_waitcnt vmcnt(" #N ")" ::: "memory")
#define LGKM_BAR asm volatile("s_waitcnt lgkmcnt(0)\n\ts_barrier" ::: "memory")

union U8 { u32 u[4]; bf16x8 v; };

__device__ __forceinline__ u16 bfbits(float f) {
  return __builtin_bit_cast(u16, (__bf16)f);   // RTN cast for the state
}

// Stage [qrow(64f) | prow(64f) | xrow(16f) | junk] into a 256-float buffer.
__device__ __forceinline__ void stage_qx(const float* rA, const float* rB,
                                         const float* rX, float* buf, int lane) {
  const float* src;
  if (lane < 16)      src = rA + 4 * lane;
  else if (lane < 32) src = rB + 4 * (lane - 16);
  else if (lane < 36) src = rX + 4 * (lane - 32);
  else                src = rX;     // dummy, keeps vmcnt accounting uniform
  gload_lds16(src, buf);
}

__global__ __launch_bounds__(TPB, 1) void qsm_main(
    const float* __restrict__ pl, const float* __restrict__ ql,
    const float* __restrict__ pu, const float* __restrict__ qu,
    const float* __restrict__ a,  const float* __restrict__ x,
    float* __restrict__ out, float* __restrict__ ws)
{
  // ~26 KB LDS; grid 512 -> 2 WGs/CU.
  __shared__ __align__(16) u16 Ab[2][MM * ASTR];     // 16.9 KB (bf16 A tiles)
  __shared__ __align__(16) u16 fcb[2][DD * FSTR];    // 4.2 KB state (f^T, bf16)
  __shared__ __align__(16) float qxs[4][256];        // 4 KB ring
  __shared__ float opart[2][MM];                     // 0.5 KB

  const int t = (int)threadIdx.x;
  const int l = t & 63;
  const int w = t >> 6;          // wave = M-tile 0..3
  const int d = l & 15;
  const int lg = l >> 4;
  const u16* au = (const u16*)a;

  const bool isFwd = ((int)blockIdx.x < GG);
  const int j = isFwd ? (int)blockIdx.x : (int)blockIdx.x - GG;
  const int lo = j * CC, hi = lo + CC;

  const int qoff = 16 * w + 4 * lg;
  const int arow = (16 * w + d) * ASTR;            // fwd frag row base
  const int frow = d * FSTR;                       // state frag row base
  const int fcw  = d * FSTR + 16 * w + 4 * lg;     // state write base

// Load the 16 bf16 rows (odd ushorts) of wave w's quarter of tile TILE.
#define D16LOAD(RH, TILE) do {                                                 \
    size_t b_ = ((size_t)(TILE) * 4096 + 16 * w * 64 + l) * 2 + 1;             \
    _Pragma("unroll")                                                          \
    for (int r_ = 0; r_ < 16; ++r_) RH[r_] = au[b_ + r_ * 128];                \
  } while (0)

// Write wave w's 16 rows into Ab[(S)&1] (lane l -> column l, conflict-free).
#define STAGEWR(S, RH) { u16* abw_ = Ab[(S) & 1];                              \
    _Pragma("unroll")                                                          \
    for (int r_ = 0; r_ < 16; ++r_) abw_[(16 * w + r_) * ASTR + l] = RH[r_]; }

#define QX_FRAGS(S)                                                            \
    const u16* fr_ = fcb[(S) & 1];                                             \
    U8 B0_, B1_;                                                               \
    _Pragma("unroll")                                                          \
    for (int e_ = 0; e_ < 4; ++e_) {                                           \
      B0_.u[e_] = *(const u32*)(fr_ + frow + 8 * lg + 2 * e_);                 \
      B1_.u[e_] = *(const u32*)(fr_ + frow + 32 + 8 * lg + 2 * e_);            \
    }                                                                          \
    const float* qx_ = qxs[(S) & 3];                                           \
    float4 qv_ = *(const float4*)(qx_ + qoff);                                 \
    float4 pv4_ = *(const float4*)(qx_ + 64 + qoff);                           \
    float xv_ = qx_[128 + d];

#define AFRAG_FWD(S)                                                           \
    U8 A0_, A1_;                                                               \
    { const u16* ab_ = Ab[(S) & 1];                                            \
      _Pragma("unroll")                                                        \
      for (int e_ = 0; e_ < 4; ++e_) {                                         \
        A0_.u[e_] = *(const u32*)(ab_ + arow + 8 * lg + 2 * e_);               \
        A1_.u[e_] = *(const u32*)(ab_ + arow + 32 + 8 * lg + 2 * e_);          \
      } }

#define AFRAG_BWD(S)                                                           \
    U8 A0_, A1_;                                                               \
    { const u16* ab_ = Ab[(S) & 1];                                            \
      u16 hv_[16];                                                             \
      _Pragma("unroll")                                                        \
      for (int e_ = 0; e_ < 8; ++e_) {                                         \
        hv_[e_]     = ab_[(8 * lg + e_) * ASTR + 16 * w + d];                  \
        hv_[8 + e_] = ab_[(32 + 8 * lg + e_) * ASTR + 16 * w + d];             \
      }                                                                        \
      _Pragma("unroll")                                                        \
      for (int e_ = 0; e_ < 4; ++e_) {                                         \
        A0_.u[e_] = (u32)hv_[2 * e_] | ((u32)hv_[2 * e_ + 1] << 16);           \
        A1_.u[e_] = (u32)hv_[8 + 2 * e_] | ((u32)hv_[8 + 2 * e_ + 1] << 16);   \
      } }

#define OUT_STORE(S, OUTP, IO_OK, IO_IDX)                                      \
    if (t < 16 && (S) >= 1) {                                                  \
      int io_ = (IO_IDX); (void)io_;                                           \
      if (IO_OK) {                                                             \
        const float* op_ = opart[((S) - 1) & 1];                               \
        OUTP[(size_t)io_ * 16 + t] =                                           \
            op_[t] + op_[16 + t] + op_[32 + t] + op_[48 + t];                  \
      }                                                                        \
    }

#define TAIL(S)                                                                \
    {                                                                          \
      f32x4 c_, z_;                                                            \
      c_[0] = qv_.x * xv_; c_[1] = qv_.y * xv_;                                \
      c_[2] = qv_.z * xv_; c_[3] = qv_.w * xv_;                                \
      z_[0] = 0.f; z_[1] = 0.f; z_[2] = 0.f; z_[3] = 0.f;                      \
      c_ = __builtin_amdgcn_mfma_f32_16x16x32_bf16(A0_.v, B0_.v, c_, 0, 0, 0); \
      z_ = __builtin_amdgcn_mfma_f32_16x16x32_bf16(A1_.v, B1_.v, z_, 0, 0, 0); \
      c_[0] += z_[0]; c_[1] += z_[1]; c_[2] += z_[2]; c_[3] += z_[3];          \
      u16* fw_ = fcb[((S) + 1) & 1];                                           \
      u32 p01_ = (u32)bfbits(c_[0]) | ((u32)bfbits(c_[1]) << 16);              \
      u32 p23_ = (u32)bfbits(c_[2]) | ((u32)bfbits(c_[3]) << 16);              \
      *(u32*)(fw_ + fcw) = p01_;                                               \
      *(u32*)(fw_ + fcw + 2) = p23_;                                           \
      float pv_ = pv4_.x * c_[0] + pv4_.y * c_[1] +                            \
                  pv4_.z * c_[2] + pv4_.w * c_[3];                             \
      pv_ += __shfl_xor(pv_, 16, 64);                                          \
      pv_ += __shfl_xor(pv_, 32, 64);                                          \
      if (l < 16) opart[(S) & 1][w * 16 + d] = pv_;                            \
    }                                                                          \
    LGKM_BAR;

  u16 H0[16], H1[16], H2[16];

  if (isFwd) {
    // f[i] = a[i] @ f[i-1] + outer(ql[i], x[i]);  lower[i] = pl[i]^T f[i]
    const int lo0 = (lo >= KK) ? lo - KK : 0;
    const int len = hi - lo0;

#define FWD_BODY(S, HL, HS) do {                                               \
    AFRAG_FWD(S)                                                               \
    QX_FRAGS(S)                                                                \
    int i3_ = lo0 + (S) + 3; if (i3_ > hi - 1) i3_ = hi - 1;                   \
    D16LOAD(HL, i3_);                                                          \
    if (w == 0) stage_qx(ql + (size_t)i3_ * 64, pl + (size_t)i3_ * 64,         \
                         x + (size_t)i3_ * 16, qxs[((S) + 3) & 3], l);         \
    VMWAIT(32);                                                                \
    OUT_STORE(S, out, io_ >= lo, lo0 + (S) - 1)                                \
    STAGEWR((S) + 1, HS)                                                       \
    TAIL(S)                                                                    \
  } while (0)

    D16LOAD(H0, lo0);
    if (w == 0) stage_qx(ql + (size_t)lo0 * 64, pl + (size_t)lo0 * 64,
                         x + (size_t)lo0 * 16, qxs[0], l);
    D16LOAD(H1, lo0 + 1);
    if (w == 0) stage_qx(ql + (size_t)(lo0 + 1) * 64, pl + (size_t)(lo0 + 1) * 64,
                         x + (size_t)(lo0 + 1) * 16, qxs[1], l);
    D16LOAD(H2, lo0 + 2);
    if (w == 0) stage_qx(ql + (size_t)(lo0 + 2) * 64, pl + (size_t)(lo0 + 2) * 64,
                         x + (size_t)(lo0 + 2) * 16, qxs[2], l);
    VMWAIT(32);                               // tile0 (+qx0) resident
    STAGEWR(0, H0)
    for (int z = t; z < DD * FSTR; z += TPB) fcb[0][z] = 0;   // zero state
    LGKM_BAR;

    int s = 0;
    while (true) {
      FWD_BODY(s, H0, H1); if (++s == len) break;
      FWD_BODY(s, H1, H2); if (++s == len) break;
      FWD_BODY(s, H2, H0); if (++s == len) break;
    }
    if (t < 16) {   // last row hi-1
      const float* op_ = opart[(len - 1) & 1];
      out[(size_t)(hi - 1) * 16 + t] = op_[t] + op_[16 + t] + op_[32 + t] + op_[48 + t];
    }
  } else {
    // g[i] = a[i+1]^T g[i+1] + outer(pu[i], x[i]); upper[n] = qu[n]^T g[n+1]
    const int ist = ((hi - 1 + KK) <= (NN - 1)) ? hi - 1 + KK : NN - 1;
    const int len = ist - lo;     // i = ist .. lo+1

#define BWD_BODY(S, HL, HS) do {                                               \
    AFRAG_BWD(S)                                                               \
    QX_FRAGS(S)                                                                \
    int i3_ = ist - (S) - 3; if (i3_ < lo + 1) i3_ = lo + 1;                   \
    int tl_ = i3_ + 1; if (tl_ > NN - 1) tl_ = NN - 1;                         \
    D16LOAD(HL, tl_);                                                          \
    if (w == 0) stage_qx(pu + (size_t)i3_ * 64, qu + (size_t)(i3_ - 1) * 64,   \
                         x + (size_t)i3_ * 16, qxs[((S) + 3) & 3], l);         \
    VMWAIT(32);                                                                \
    OUT_STORE(S, ws, io_ <= hi - 1, ist - (S))                                 \
    STAGEWR((S) + 1, HS)                                                       \
    TAIL(S)                                                                    \
  } while (0)

    { int tl = (ist + 1 <= NN - 1) ? ist + 1 : NN - 1;   // step0 tile a[i+1]
      D16LOAD(H0, tl); }
    if (w == 0) stage_qx(pu + (size_t)ist * 64, qu + (size_t)(ist - 1) * 64,
                         x + (size_t)ist * 16, qxs[0], l);
    D16LOAD(H1, ist);                                    // step1 tile
    if (w == 0) stage_qx(pu + (size_t)(ist - 1) * 64, qu + (size_t)(ist - 2) * 64,
                         x + (size_t)(ist - 1) * 16, qxs[1], l);
    D16LOAD(H2, ist - 1);                                // step2 tile
    if (w == 0) stage_qx(pu + (size_t)(ist - 2) * 64, qu + (size_t)(ist - 3) * 64,
                         x + (size_t)(ist - 2) * 16, qxs[2], l);
    VMWAIT(32);
    STAGEWR(0, H0)
    for (int z = t; z < DD * FSTR; z += TPB) fcb[0][z] = 0;
    LGKM_BAR;

    int s = 0;
    while (true) {
      BWD_BODY(s, H0, H1); if (++s == len) break;
      BWD_BODY(s, H1, H2); if (++s == len) break;
      BWD_BODY(s, H2, H0); if (++s == len) break;
    }
    if (t < 16) {   // upper[lo] = qu[lo] . g[lo+1]
      const float* op_ = opart[(len - 1) & 1];
      ws[(size_t)lo * 16 + t] = op_[t] + op_[16 + t] + op_[32 + t] + op_[48 + t];
      if (j == GG - 1) ws[(size_t)(NN - 1) * 16 + t] = 0.0f;  // upper[N-1]=0
    }
  }
}

__global__ void add_ws_kernel(float* __restrict__ out, const float* __restrict__ ws) {
  const int i = (int)blockIdx.x * (int)blockDim.x + (int)threadIdx.x;
  float4 o = ((const float4*)out)[i];
  const float4 u = ((const float4*)ws)[i];
  o.x += u.x; o.y += u.y; o.z += u.z; o.w += u.w;
  ((float4*)out)[i] = o;
}

extern "C" void kernel_launch(void* const* d_in, const int* in_sizes, int n_in,
                              void* d_out, int out_size, void* d_ws, size_t ws_size,
                              hipStream_t stream) {
  const float* pl = (const float*)d_in[0];
  const float* ql = (const float*)d_in[1];
  const float* pu = (const float*)d_in[2];
  const float* qu = (const float*)d_in[3];
  const float* a  = (const float*)d_in[4];
  // d_in[5] = idx (arange(N), identity gather -- folded into the algorithm)
  const float* x  = (const float*)d_in[6];
  float* out = (float*)d_out;
  float* ws  = (float*)d_ws;   // upper-part scratch: N*D floats = 1 MB

  qsm_main<<<2 * GG, TPB, 0, stream>>>(pl, ql, pu, qu, a, x, out, ws);
  add_ws_kernel<<<(NN * DD / 4) / 256, 256, 0, stream>>>(out, ws);
}

// Round 10
// 94.229 us; speedup vs baseline: 1.2856x; 1.2856x over previous
//
#include <hip/hip_runtime.h>
#include <cstdint>
#include <cstddef>

// N=16384, M=64, D=16.  Split-chunk scheme, grid = 512 (2 WGs per 64-row
// chunk, co-located on one XCD via bid%8-preserving mapping, 2 WG/CU):
//   h=0: forward recurrence + lower  (verbatim round-3 kernel, proven)
//   h=1: upper via the Z-matrix ascending sweep:
//        upper[n] = sum_{m>n} (z[n,m].pu[m]) x[m], z[n,n+1]=qu[n],
//        z[n,m]=a[m] z[n,m-1]  -- one 64x64x64 MFMA batch per tile.
// Both WGs stream the same A-tiles (L2-dedup) => ~half the HBM bytes of
// separate fwd/bwd sweeps (the measured ~6.5 TB/s stream was the limiter).
#define NN 16384
#define MM 64
#define DD 16
#define CC 64
#define KKF 12              // fwd warm-up (contractive A: 0.5^12 ~ 2e-4)
#define KKZ 8               // upper tail steps per column
#define GG (NN / CC)        // 256 chunks
#define TPB 256             // 4 waves
#define FSTR 72             // fwd state stride (u16) -> conflict-free
#define FZ 72               // Z^T row stride (u16)

typedef __attribute__((ext_vector_type(8))) __bf16 bf16x8;
typedef __attribute__((ext_vector_type(4))) float f32x4;
typedef unsigned short u16;
typedef unsigned int u32;

typedef const __attribute__((address_space(1))) void* gas_t;
typedef __attribute__((address_space(3))) void* sas_t;

__device__ __forceinline__ void gload_lds16(const void* g, void* l) {
  __builtin_amdgcn_global_load_lds((gas_t)g, (sas_t)l, 16, 0, 0);
}
#define VMWAIT(N) asm volatile("s_waitcnt vmcnt(" #N ")" ::: "memory")
#define LGKM_BAR asm volatile("s_waitcnt lgkmcnt(0)\n\ts_barrier" ::: "memory")

__device__ __forceinline__ u16 bfbits(float f) {
  return __builtin_bit_cast(u16, (__bf16)f);   // RTN
}
__device__ __forceinline__ u32 pk2(float a, float b) {
  return (u32)bfbits(a) | ((u32)bfbits(b) << 16);
}
__device__ __forceinline__ bf16x8 cvt8p(float4 a, float4 b) {
  bf16x8 r;
  r[0] = (__bf16)a.x; r[1] = (__bf16)a.y; r[2] = (__bf16)a.z; r[3] = (__bf16)a.w;
  r[4] = (__bf16)b.x; r[5] = (__bf16)b.y; r[6] = (__bf16)b.z; r[7] = (__bf16)b.w;
  return r;
}

// h=0 qx slot: [ql row | pl row | x row | pad]
__device__ __forceinline__ void stage_qx3(const float* rA, const float* rB,
                                          const float* rX, float* buf, int lane) {
  const float* src;
  if (lane < 16)      src = rA + 4 * lane;
  else if (lane < 32) src = rB + 4 * (lane - 16);
  else if (lane < 36) src = rX + 4 * (lane - 32);
  else                src = rX;
  gload_lds16(src, buf);
}
// h=1 qx slot: [pu row | qu row | x row | pad]
__device__ __forceinline__ void stage_zqx(const float* pu_, const float* qu_,
                                          const float* x_, float* buf, int lane) {
  const float* src;
  if (lane < 16)      src = pu_ + 4 * lane;
  else if (lane < 32) src = qu_ + 4 * (lane - 16);
  else if (lane < 36) src = x_ + 4 * (lane - 32);
  else                src = x_;
  gload_lds16(src, buf);
}

__global__ __launch_bounds__(TPB, 2) void qsm_split(
    const float* __restrict__ pl, const float* __restrict__ ql,
    const float* __restrict__ pu, const float* __restrict__ qu,
    const float* __restrict__ a,  const float* __restrict__ x,
    float* __restrict__ out, float* __restrict__ ws)
{
  // ~42 KB total -> 2 WGs/CU.
  __shared__ __align__(16) __bf16 Ab[2][MM * MM];     // 16 KB tiles (both h)
  __shared__ __align__(16) u16 Zb[2][MM * FZ];        // 18 KB Z^T (h=1)
  __shared__ __align__(16) __bf16 fcb[2][DD * FSTR];  // 4.5 KB f^T (h=0)
  __shared__ __align__(16) float qxs[3][256];         // 3 KB ring
  __shared__ float opart[2][MM];                      // 0.5 KB (h=0)

  const int t = (int)threadIdx.x;
  const int l = t & 63;
  const int w = t >> 6;
  const int d = l & 15;
  const int lg = l >> 4;

  const int bid = (int)blockIdx.x;
  const int h = (bid >> 3) & 1;                  // half: 0=fwd/lower, 1=upper
  const int j = (bid & 7) | ((bid >> 4) << 3);   // chunk; bid%8 == j%8 (XCD)
  const int lo = j * CC, hi = lo + CC;

  // staging-write offsets (both halves): thread t holds A[r][16f], r=t>>2
  const int swr = t >> 2, swp = 2 * (t & 3);
  const int wo0 = (swr * 8 + ((swp) ^ (swr & 7))) * 8;
  const int wo1 = (swr * 8 + ((swp + 1) ^ (swr & 7))) * 8;

#define LOADT(RS, TILE) {                                                      \
    const float4* p4_ = (const float4*)(a + (size_t)(TILE) * 4096 + t * 16);   \
    RS[0] = p4_[0]; RS[1] = p4_[1]; RS[2] = p4_[2]; RS[3] = p4_[3]; }

#define STAGEWR(S, RH) { __bf16* aw_ = Ab[(S) & 1];                            \
    *(bf16x8*)(aw_ + wo0) = cvt8p(RH[0], RH[1]);                               \
    *(bf16x8*)(aw_ + wo1) = cvt8p(RH[2], RH[3]); }

  if (h == 0) {
    // ---------------- forward + lower (round-3 verbatim) ----------------
    const int qoff = 16 * w + 4 * lg;
    const int rf = 16 * w + (l & 15);
    const int afr0 = (rf * 8 + (lg ^ (rf & 7))) * 8;
    const int afr1 = (rf * 8 + ((4 + lg) ^ (rf & 7))) * 8;
    const int bfr0 = d * FSTR + lg * 8;
    const int bfr1 = d * FSTR + (4 + lg) * 8;
    const int fcw  = d * FSTR + 16 * w + 4 * lg;

#define FRAG_READS(S)                                                          \
    const __bf16* ab_ = Ab[(S) & 1];                                           \
    const __bf16* fr_ = fcb[(S) & 1];                                          \
    const float* qx_ = qxs[(S) % 3];                                           \
    bf16x8 a0_ = *(const bf16x8*)(ab_ + afr0);                                 \
    bf16x8 b0_ = *(const bf16x8*)(fr_ + bfr0);                                 \
    bf16x8 a1_ = *(const bf16x8*)(ab_ + afr1);                                 \
    bf16x8 b1_ = *(const bf16x8*)(fr_ + bfr1);                                 \
    float4 qv_ = *(const float4*)(qx_ + qoff);                                 \
    float4 pv4_ = *(const float4*)(qx_ + 64 + qoff);                           \
    float xv_ = qx_[128 + d];

#define COMPUTE_TAIL(S)                                                        \
    {                                                                          \
      f32x4 c_, z_;                                                            \
      c_[0] = qv_.x * xv_; c_[1] = qv_.y * xv_;                                \
      c_[2] = qv_.z * xv_; c_[3] = qv_.w * xv_;                                \
      z_[0] = 0.f; z_[1] = 0.f; z_[2] = 0.f; z_[3] = 0.f;                      \
      c_ = __builtin_amdgcn_mfma_f32_16x16x32_bf16(a0_, b0_, c_, 0, 0, 0);     \
      z_ = __builtin_amdgcn_mfma_f32_16x16x32_bf16(a1_, b1_, z_, 0, 0, 0);     \
      c_[0] += z_[0]; c_[1] += z_[1]; c_[2] += z_[2]; c_[3] += z_[3];          \
      __bf16* fw_ = fcb[((S) + 1) & 1];                                        \
      *(u32*)((u16*)fw_ + fcw)     = pk2(c_[0], c_[1]);                        \
      *(u32*)((u16*)fw_ + fcw + 2) = pk2(c_[2], c_[3]);                        \
      float pv_ = pv4_.x * c_[0] + pv4_.y * c_[1] +                            \
                  pv4_.z * c_[2] + pv4_.w * c_[3];                             \
      pv_ += __shfl_xor(pv_, 16, 64);                                          \
      pv_ += __shfl_xor(pv_, 32, 64);                                          \
      if (l < 16) opart[(S) & 1][w * 16 + d] = pv_;                            \
    }                                                                          \
    LGKM_BAR;

#define OUT_STORE(S)                                                           \
    if (t < 16 && (S) >= 1) {                                                  \
      int io_ = lo0 + (S) - 1;                                                 \
      if (io_ >= lo) {                                                         \
        const float* op_ = opart[((S) - 1) & 1];                               \
        out[(size_t)io_ * 16 + t] =                                            \
            op_[t] + op_[16 + t] + op_[32 + t] + op_[48 + t];                  \
      }                                                                        \
    }

#define FWD_BODY(S, RW, RL) do {                                               \
    FRAG_READS(S)                                                              \
    int i2_ = lo0 + (S) + 2; if (i2_ > hi - 1) i2_ = hi - 1;                   \
    LOADT(RL, i2_);                                                            \
    if (w == 0)                                                                \
      stage_qx3(ql + (size_t)i2_ * 64, pl + (size_t)i2_ * 64,                  \
                x + (size_t)i2_ * 16, qxs[((S) + 2) % 3], l);                  \
    if (w == 0) VMWAIT(5); else VMWAIT(4);                                     \
    STAGEWR((S) + 1, RW)                                                       \
    OUT_STORE(S)                                                               \
    COMPUTE_TAIL(S)                                                            \
  } while (0)

    const int lo0 = (lo >= KKF) ? lo - KKF : 0;
    const int len = hi - lo0;
    float4 RA[4], RB[4];

    LOADT(RA, lo0);
    if (w == 0) stage_qx3(ql + (size_t)lo0 * 64, pl + (size_t)lo0 * 64,
                          x + (size_t)lo0 * 16, qxs[0], l);
    LOADT(RB, lo0 + 1);
    if (w == 0) stage_qx3(ql + (size_t)(lo0 + 1) * 64, pl + (size_t)(lo0 + 1) * 64,
                          x + (size_t)(lo0 + 1) * 16, qxs[1], l);
    if (w == 0) VMWAIT(5); else VMWAIT(4);
    STAGEWR(0, RA)
    for (int z = 4 * t; z < DD * FSTR; z += 4 * TPB) {   // zero initial state
      __bf16* z_ = fcb[0] + z;
      z_[0] = (__bf16)0.f; z_[1] = (__bf16)0.f;
      z_[2] = (__bf16)0.f; z_[3] = (__bf16)0.f;
    }
    LGKM_BAR;

    int s = 0;
    while (true) {
      FWD_BODY(s, RB, RA); if (++s == len) break;
      FWD_BODY(s, RA, RB); if (++s == len) break;
    }
    if (t < 16) {   // last row hi-1
      const float* op_ = opart[(len - 1) & 1];
      out[(size_t)(hi - 1) * 16 + t] = op_[t] + op_[16 + t] + op_[32 + t] + op_[48 + t];
    }
  } else {
    // ---------------- upper via Z-matrix ascending sweep ----------------
    // Step S handles tile tt = lo+1+S:  Z <- A[tt] Z (MFMA), insert column
    // ci=S (= qu[tt-1]) as the SOLE writer of that column (no WAW), coeff =
    // pu[tt].Z'[:,c] (+ qu.pu for the fresh column), o4 += coeff * x[tt].
    const int myc = 16 * w + d;                // owned Z column
    int afz[4][2];
#pragma unroll
    for (int rb = 0; rb < 4; ++rb)
#pragma unroll
      for (int kh = 0; kh < 2; ++kh)
        afz[rb][kh] = ((16 * rb + d) * 8 + ((4 * kh + lg) ^ ((16 * rb + d) & 7))) * 8;
    const int zr0 = myc * FZ + 8 * lg;
    const int zr1 = zr0 + 32;

    const int mend = (hi - 1 + KKZ <= NN - 1) ? hi - 1 + KKZ : NN - 1;
    const int lenz = mend - lo;                // 63..71 steps
    float4 o4; o4.x = 0.f; o4.y = 0.f; o4.z = 0.f; o4.w = 0.f;

    for (int z = t; z < 2 * MM * FZ; z += TPB) ((u16*)Zb)[z] = 0;

#define ZBODY(S, RW, RL) do {                                                  \
    const __bf16* ab_ = Ab[(S) & 1];                                           \
    bf16x8 Af_[4][2];                                                          \
    _Pragma("unroll")                                                          \
    for (int rb = 0; rb < 4; ++rb)                                             \
      _Pragma("unroll")                                                        \
      for (int kh = 0; kh < 2; ++kh)                                           \
        Af_[rb][kh] = *(const bf16x8*)(ab_ + afz[rb][kh]);                     \
    const u16* zb_ = (const u16*)Zb[(S) & 1];                                  \
    bf16x8 ZB0_ = *(const bf16x8*)((const __bf16*)(zb_ + zr0));                \
    bf16x8 ZB1_ = *(const bf16x8*)((const __bf16*)(zb_ + zr1));                \
    const float* qx_ = qxs[(S) % 3];                                           \
    float4 pu4_[4];                                                            \
    _Pragma("unroll")                                                          \
    for (int rb = 0; rb < 4; ++rb)                                             \
      pu4_[rb] = *(const float4*)(qx_ + 16 * rb + 4 * lg);                     \
    const float puL_ = qx_[l];                                                 \
    const float quL_ = qx_[64 + l];                                            \
    const float4 x4_ = *(const float4*)(qx_ + 128 + 4 * lg);                   \
    { int i2_ = lo + 1 + (S) + 2; if (i2_ > mend) i2_ = mend;                  \
      LOADT(RL, i2_);                                                          \
      if (w == 0)                                                              \
        stage_zqx(pu + (size_t)i2_ * 64, qu + (size_t)(i2_ - 1) * 64,          \
                  x + (size_t)i2_ * 16, qxs[((S) + 2) % 3], l); }              \
    if (w == 0) VMWAIT(5); else VMWAIT(4);                                     \
    STAGEWR((S) + 1, RW)                                                       \
    const int cins_ = ((S) < CC) ? (S) : -1;                                   \
    u16* zw_ = (u16*)Zb[((S) + 1) & 1];                                        \
    float coeffp_ = 0.f;                                                       \
    _Pragma("unroll")                                                          \
    for (int rb = 0; rb < 4; ++rb) {                                           \
      f32x4 cz_; cz_[0] = 0.f; cz_[1] = 0.f; cz_[2] = 0.f; cz_[3] = 0.f;       \
      cz_ = __builtin_amdgcn_mfma_f32_16x16x32_bf16(Af_[rb][0], ZB0_, cz_, 0, 0, 0); \
      cz_ = __builtin_amdgcn_mfma_f32_16x16x32_bf16(Af_[rb][1], ZB1_, cz_, 0, 0, 0); \
      if (myc != cins_) {                                                      \
        const int zo_ = myc * FZ + 16 * rb + 4 * lg;                           \
        *(u32*)(zw_ + zo_)     = pk2(cz_[0], cz_[1]);                          \
        *(u32*)(zw_ + zo_ + 2) = pk2(cz_[2], cz_[3]);                          \
      }                                                                        \
      coeffp_ += pu4_[rb].x * cz_[0] + pu4_[rb].y * cz_[1] +                   \
                 pu4_[rb].z * cz_[2] + pu4_[rb].w * cz_[3];                    \
    }                                                                          \
    coeffp_ += __shfl_xor(coeffp_, 16, 64);                                    \
    coeffp_ += __shfl_xor(coeffp_, 32, 64);                                    \
    if (cins_ >= 0 && w == (cins_ >> 4)) {                                     \
      zw_[cins_ * FZ + l] = bfbits(quL_);         /* sole writer of col ci */  \
      float dv_ = quL_ * puL_;                                                 \
      dv_ += __shfl_xor(dv_, 1, 64);  dv_ += __shfl_xor(dv_, 2, 64);           \
      dv_ += __shfl_xor(dv_, 4, 64);  dv_ += __shfl_xor(dv_, 8, 64);           \
      dv_ += __shfl_xor(dv_, 16, 64); dv_ += __shfl_xor(dv_, 32, 64);          \
      if (d == (cins_ & 15)) coeffp_ += dv_;                                   \
    }                                                                          \
    o4.x += coeffp_ * x4_.x; o4.y += coeffp_ * x4_.y;                          \
    o4.z += coeffp_ * x4_.z; o4.w += coeffp_ * x4_.w;                          \
    LGKM_BAR;                                                                  \
  } while (0)

    float4 RA[4], RB[4];
    LOADT(RA, lo + 1);
    if (w == 0) stage_zqx(pu + (size_t)(lo + 1) * 64, qu + (size_t)lo * 64,
                          x + (size_t)(lo + 1) * 16, qxs[0], l);
    { int t1 = (lo + 2 > mend) ? mend : lo + 2;
      LOADT(RB, t1);
      if (w == 0) stage_zqx(pu + (size_t)t1 * 64, qu + (size_t)(t1 - 1) * 64,
                            x + (size_t)t1 * 16, qxs[1], l); }
    if (w == 0) VMWAIT(5); else VMWAIT(4);
    STAGEWR(0, RA)
    LGKM_BAR;

    int s = 0;
    while (true) {
      ZBODY(s, RB, RA); if (++s == lenz) break;
      ZBODY(s, RA, RB); if (++s == lenz) break;
    }
    // lane (w,d,lg) owns upper row lo+16w+d, cols 4lg..4lg+3
    *(float4*)(ws + (size_t)(lo + 16 * w + d) * 16 + 4 * lg) = o4;
  }
}

__global__ void add_ws_kernel(float* __restrict__ out, const float* __restrict__ ws) {
  const int i = (int)blockIdx.x * (int)blockDim.x + (int)threadIdx.x;
  float4 o = ((const float4*)out)[i];
  const float4 u = ((const float4*)ws)[i];
  o.x += u.x; o.y += u.y; o.z += u.z; o.w += u.w;
  ((float4*)out)[i] = o;
}

extern "C" void kernel_launch(void* const* d_in, const int* in_sizes, int n_in,
                              void* d_out, int out_size, void* d_ws, size_t ws_size,
                              hipStream_t stream) {
  const float* pl = (const float*)d_in[0];
  const float* ql = (const float*)d_in[1];
  const float* pu = (const float*)d_in[2];
  const float* qu = (const float*)d_in[3];
  const float* a  = (const float*)d_in[4];
  // d_in[5] = idx (arange(N), identity gather -- folded into the algorithm)
  const float* x  = (const float*)d_in[6];
  float* out = (float*)d_out;
  float* ws  = (float*)d_ws;   // upper-part scratch: N*D floats = 1 MB

  qsm_split<<<2 * GG, TPB, 0, stream>>>(pl, ql, pu, qu, a, x, out, ws);
  add_ws_kernel<<<(NN * DD / 4) / 256, 256, 0, stream>>>(out, ws);
}